// Round 2
// baseline (299.531 us; speedup 1.0000x reference)
//
#include <hip/hip_runtime.h>
#include <math.h>

// Problem constants
#define BB 32
#define SS 50
#define LL 16
#define CC 50
#define CP 52          // C padded to 52 (13 chunks of 4)
#define DD 64
#define NW 13          // c-chunks per batch element
#define H4 256
#define NROWS_Q (BB*SS)        // 1600
#define NROWS_L (BB*SS*LL)     // 25600
#define NROWS_T (NROWS_L + NROWS_Q)  // 27200

// ---------------- workspace layout (in floats) ----------------
#define OFF_QCW    0                         // 1600*52
#define OFF_QE     (OFF_QCW  + NROWS_Q*CP)
#define OFF_QER    (OFF_QE   + NROWS_Q*DD)
#define OFF_QAD    (OFF_QER  + NROWS_Q*DD)
#define OFF_LCW    (OFF_QAD  + NROWS_Q*DD)   // 25600*52
#define OFF_LER    (OFF_LCW  + NROWS_L*CP)
#define OFF_LAD    (OFF_LER  + NROWS_L*DD)
#define OFF_LELAST (OFF_LAD  + NROWS_L*DD)   // 1600*64
#define OFF_PQ     (OFF_LELAST + NROWS_Q*DD) // 1600*13*64
#define OFF_PL     (OFF_PQ   + NROWS_Q*NW*DD)
// total ≈ 7.76M floats ≈ 29.6 MB

// =====================================================================
// K0 (merged): all row-parallel precompute. One wave per row.
//   rows [0, NROWS_L):              l-side  (x = q_embed[l_data])
//     l_cw = softmax(x@K^T) pad52, l_er = sigmoid(x@W_e+b_e),
//     l_ad = tanh(x@W_a+b_a), le_last (l==15 rows)
//   rows [NROWS_L, NROWS_T):        q-side  (xq = q_embed[q_data],
//     xa = qa_embed[qa_data])
//     q_cw = softmax(xq@K^T) pad52, q_er = sigmoid(xa@W_e+b_e),
//     q_ad = tanh(xa@W_a+b_a), q_e = xq
// Branch on row-range is wave-uniform.
// =====================================================================
__global__ __launch_bounds__(256) void k0_kernel(
    const int* __restrict__ qd, const int* __restrict__ qadx,
    const int* __restrict__ ld,
    const float* __restrict__ Kmat, const float* __restrict__ qemb,
    const float* __restrict__ qaemb,
    const float* __restrict__ We, const float* __restrict__ Wa,
    const float* __restrict__ be, const float* __restrict__ ba,
    float* __restrict__ l_cw, float* __restrict__ l_er_o,
    float* __restrict__ l_ad_o, float* __restrict__ le_last,
    float* __restrict__ q_cw, float* __restrict__ q_e_o,
    float* __restrict__ q_er_o, float* __restrict__ q_ad_o)
{
    __shared__ float2 sWEA[DD*DD];   // (W_e[k][d], W_a[k][d])
    __shared__ float  sK[DD*65];     // K[c][k], rows padded to 65, c>=50 zeroed
    int tid = threadIdx.x;
    for (int i = tid; i < DD*DD; i += 256) sWEA[i] = make_float2(We[i], Wa[i]);
    for (int i = tid; i < DD*65; i += 256) {
        int c = i / 65, k = i - c*65;
        sK[i] = (c < CC && k < DD) ? Kmat[c*DD + k] : 0.f;
    }
    __syncthreads();

    int lane = tid & 63, wv = tid >> 6;
    int wave_id = blockIdx.x*4 + wv;
    int nwaves  = gridDim.x*4;
    const float* skr = sK + lane*65;
    float bev = be[lane], bav = ba[lane];

    for (int row = wave_id; row < NROWS_T; row += nwaves) {
        if (row < NROWS_L) {
            // ---------------- l-side ----------------
            float x = qemb[(size_t)ld[row]*DD + lane];
            float er = 0.f, ad = 0.f, sc = 0.f;
            #pragma unroll
            for (int k = 0; k < DD; ++k) {
                float xk = __shfl(x, k);
                float2 w2 = sWEA[k*DD + lane];
                er = fmaf(xk, w2.x, er);
                ad = fmaf(xk, w2.y, ad);
                sc = fmaf(xk, skr[k], sc);
            }
            float s = (lane < CC) ? sc : -1e30f;
            float mx = s;
            #pragma unroll
            for (int o = 32; o >= 1; o >>= 1) mx = fmaxf(mx, __shfl_xor(mx, o));
            float p = (lane < CC) ? expf(s - mx) : 0.f;
            float sum = p;
            #pragma unroll
            for (int o = 32; o >= 1; o >>= 1) sum += __shfl_xor(sum, o);
            float wsm = p / sum;

            l_er_o[(size_t)row*DD + lane] = 1.f / (1.f + expf(-(er + bev)));
            l_ad_o[(size_t)row*DD + lane] = tanhf(ad + bav);
            if (lane < CP) l_cw[(size_t)row*CP + lane] = (lane < CC) ? wsm : 0.f;
            if ((row & (LL-1)) == (LL-1)) le_last[(size_t)(row >> 4)*DD + lane] = x;
        } else {
            // ---------------- q-side ----------------
            int qrow = row - NROWS_L;
            float xq = qemb [(size_t)qd  [qrow]*DD + lane];
            float xa = qaemb[(size_t)qadx[qrow]*DD + lane];
            float er = 0.f, ad = 0.f, sc = 0.f;
            #pragma unroll
            for (int k = 0; k < DD; ++k) {
                float xqk = __shfl(xq, k);
                float xak = __shfl(xa, k);
                float2 w2 = sWEA[k*DD + lane];
                er = fmaf(xak, w2.x, er);
                ad = fmaf(xak, w2.y, ad);
                sc = fmaf(xqk, skr[k], sc);
            }
            float s = (lane < CC) ? sc : -1e30f;
            float mx = s;
            #pragma unroll
            for (int o = 32; o >= 1; o >>= 1) mx = fmaxf(mx, __shfl_xor(mx, o));
            float p = (lane < CC) ? expf(s - mx) : 0.f;
            float sum = p;
            #pragma unroll
            for (int o = 32; o >= 1; o >>= 1) sum += __shfl_xor(sum, o);
            float wsm = p / sum;

            q_e_o [(size_t)qrow*DD + lane] = xq;
            q_er_o[(size_t)qrow*DD + lane] = 1.f / (1.f + expf(-(er + bev)));
            q_ad_o[(size_t)qrow*DD + lane] = tanhf(ad + bav);
            if (lane < CP) q_cw[(size_t)qrow*CP + lane] = (lane < CC) ? wsm : 0.f;
        }
    }
}

// =====================================================================
// Phase A: the sequential scan, synchronization-free.
// One 64-thread block per (b, c-chunk): 32*13 = 416 blocks.
// Lane = d. M-chunk (4 rows x 64 cols) in 4 VGPRs.
// Writes PARTIAL q_read / l_read reductions; Phase B sums the 13 chunks.
// =====================================================================
__global__ __launch_bounds__(64) void phaseA_kernel(
    const float* __restrict__ M0,
    const float* __restrict__ q_cw, const float* __restrict__ q_er,
    const float* __restrict__ q_ad,
    const float* __restrict__ l_cw, const float* __restrict__ l_er,
    const float* __restrict__ l_ad,
    float* __restrict__ Pq, float* __restrict__ Pl)
{
    int wid = blockIdx.x;
    int b = wid / NW, om = wid % NW;
    int c0 = om * 4, d = threadIdx.x;

    float M[4];
    #pragma unroll
    for (int i = 0; i < 4; ++i) {
        int c = c0 + i;
        M[i] = (c < CC) ? M0[c*DD + d] : 0.f;
    }

    const float* qcw = q_cw + (size_t)b*SS*CP + c0;
    const float* qer = q_er + (size_t)b*SS*DD + d;
    const float* qad = q_ad + (size_t)b*SS*DD + d;
    const float* lcw = l_cw + (size_t)b*SS*LL*CP + c0;
    const float* ler = l_er + (size_t)b*SS*LL*DD + d;
    const float* lad = l_ad + (size_t)b*SS*LL*DD + d;
    float* pq = Pq + ((size_t)b*SS*NW + om)*DD + d;
    float* pl = Pl + ((size_t)b*SS*NW + om)*DD + d;

    for (int s = 0; s < SS; ++s) {
        float4 qw = *(const float4*)(qcw + s*CP);
        // q_read partial (M at start of step)
        float qr;
        qr = qw.x * M[0];
        qr = fmaf(qw.y, M[1], qr);
        qr = fmaf(qw.z, M[2], qr);
        qr = fmaf(qw.w, M[3], qr);

        float a0 = 0.f, a1 = 0.f, a2 = 0.f, a3 = 0.f;
        #pragma unroll
        for (int l = 0; l < LL; ++l) {
            int il = s*LL + l;
            float4 lw = *(const float4*)(lcw + (size_t)il*CP);
            float e = ler[(size_t)il*DD];
            float a = lad[(size_t)il*DD];
            // read (old M) into separate acc chains
            a0 = fmaf(lw.x, M[0], a0);
            a1 = fmaf(lw.y, M[1], a1);
            a2 = fmaf(lw.z, M[2], a2);
            a3 = fmaf(lw.w, M[3], a3);
            // write: M = M + w*(a - e*M)
            M[0] = fmaf(lw.x, fmaf(-e, M[0], a), M[0]);
            M[1] = fmaf(lw.y, fmaf(-e, M[1], a), M[1]);
            M[2] = fmaf(lw.z, fmaf(-e, M[2], a), M[2]);
            M[3] = fmaf(lw.w, fmaf(-e, M[3], a), M[3]);
        }
        pq[(size_t)s*NW*DD] = qr;
        pl[(size_t)s*NW*DD] = (a0 + a1) + (a2 + a3);

        // final q-write for this step
        float e = qer[(size_t)s*DD], a = qad[(size_t)s*DD];
        M[0] = fmaf(qw.x, fmaf(-e, M[0], a), M[0]);
        M[1] = fmaf(qw.y, fmaf(-e, M[1], a), M[1]);
        M[2] = fmaf(qw.z, fmaf(-e, M[2], a), M[2]);
        M[3] = fmaf(qw.w, fmaf(-e, M[3], a), M[3]);
    }
}

// =====================================================================
// Phase B: gather partials -> mastery -> LN -> MLP -> sigmoid -> out.
// 8 rows per 256-thread block (amortizes W0/W1 traffic 8x). 200 blocks.
// =====================================================================
__global__ __launch_bounds__(256) void phaseB_kernel(
    const float* __restrict__ Pq, const float* __restrict__ Pl,
    const float* __restrict__ q_e_i, const float* __restrict__ le_last,
    const float* __restrict__ ln_g, const float* __restrict__ ln_b,
    const float* __restrict__ W0, const float* __restrict__ b0,
    const float* __restrict__ W1, const float* __restrict__ b1,
    const float* __restrict__ Wout, const float* __restrict__ bout,
    float* __restrict__ out)
{
    __shared__ float m[8][H4];
    __shared__ float h[8][H4];
    __shared__ float red[8][4];

    int j = threadIdx.x;
    int g0 = blockIdx.x * 8;
    int lane = j & 63, wv = j >> 6;

    // build mastery = [q_read | q_e | l_read | le_last]
    int seg = j >> 6, dd = j & 63;
    #pragma unroll
    for (int r = 0; r < 8; ++r) {
        int g = g0 + r;
        float v;
        if (seg == 0) {
            v = 0.f;
            for (int w = 0; w < NW; ++w) v += Pq[((size_t)g*NW + w)*DD + dd];
        } else if (seg == 1) {
            v = q_e_i[(size_t)g*DD + dd];
        } else if (seg == 2) {
            v = 0.f;
            for (int w = 0; w < NW; ++w) v += Pl[((size_t)g*NW + w)*DD + dd];
        } else {
            v = le_last[(size_t)g*DD + dd];
        }
        m[r][j] = v;
    }
    __syncthreads();

    // LayerNorm: wave wv normalizes rows wv and wv+4 (float4 per lane)
    #pragma unroll
    for (int rr = 0; rr < 2; ++rr) {
        int r = wv + rr*4;
        float4 v4 = *(((const float4*)&m[r][0]) + lane);
        float s1 = v4.x + v4.y + v4.z + v4.w;
        float s2 = v4.x*v4.x + v4.y*v4.y + v4.z*v4.z + v4.w*v4.w;
        #pragma unroll
        for (int o = 32; o >= 1; o >>= 1) {
            s1 += __shfl_xor(s1, o);
            s2 += __shfl_xor(s2, o);
        }
        float mu  = s1 * (1.f/256.f);
        float var = s2 * (1.f/256.f) - mu*mu;
        float is  = rsqrtf(var + 1e-5f);
        float4 g4 = *(((const float4*)ln_g) + lane);
        float4 b4 = *(((const float4*)ln_b) + lane);
        float4 o4;
        o4.x = (v4.x - mu)*is*g4.x + b4.x;
        o4.y = (v4.y - mu)*is*g4.y + b4.y;
        o4.z = (v4.z - mu)*is*g4.z + b4.z;
        o4.w = (v4.w - mu)*is*g4.w + b4.w;
        *(((float4*)&m[r][0]) + lane) = o4;
    }
    __syncthreads();

    // GEMM1: h0 = relu(m @ W0 + b0); thread j owns output column j, 8 rows
    float acc[8];
    {
        float bj = b0[j];
        #pragma unroll
        for (int r = 0; r < 8; ++r) acc[r] = bj;
    }
    #pragma unroll 4
    for (int k = 0; k < H4; ++k) {
        float wv0 = W0[(size_t)k*H4 + j];
        #pragma unroll
        for (int r = 0; r < 8; ++r) acc[r] = fmaf(m[r][k], wv0, acc[r]);
    }
    #pragma unroll
    for (int r = 0; r < 8; ++r) h[r][j] = fmaxf(acc[r], 0.f);
    __syncthreads();

    // GEMM2: h1 = h0 @ W1 + b1
    float a2[8];
    {
        float bj = b1[j];
        #pragma unroll
        for (int r = 0; r < 8; ++r) a2[r] = bj;
    }
    #pragma unroll 4
    for (int k = 0; k < H4; ++k) {
        float wv1 = W1[(size_t)k*H4 + j];
        #pragma unroll
        for (int r = 0; r < 8; ++r) a2[r] = fmaf(h[r][k], wv1, a2[r]);
    }

    // output: pred = sigmoid(h1 . Wout + bout)
    float wo = Wout[j];
    #pragma unroll
    for (int r = 0; r < 8; ++r) {
        float v = a2[r] * wo;
        #pragma unroll
        for (int o = 32; o >= 1; o >>= 1) v += __shfl_xor(v, o);
        if (lane == 0) red[r][wv] = v;
    }
    __syncthreads();
    if (j < 8) {
        float t = red[j][0] + red[j][1] + red[j][2] + red[j][3] + bout[0];
        out[g0 + j] = 1.f / (1.f + expf(-t));
    }
}

// =====================================================================
extern "C" void kernel_launch(void* const* d_in, const int* in_sizes, int n_in,
                              void* d_out, int out_size, void* d_ws, size_t ws_size,
                              hipStream_t stream)
{
    const int*   q_data  = (const int*)  d_in[0];
    const int*   qa_data = (const int*)  d_in[1];
    const int*   l_data  = (const int*)  d_in[2];
    // d_in[3] users: unused by reference forward
    const float* Kmat    = (const float*)d_in[4];
    const float* q_embed = (const float*)d_in[5];
    const float* qa_embed= (const float*)d_in[6];
    // d_in[7] u_embed: unused by reference forward
    const float* M0      = (const float*)d_in[8];
    const float* W_e     = (const float*)d_in[9];
    const float* b_e     = (const float*)d_in[10];
    const float* W_a     = (const float*)d_in[11];
    const float* b_a     = (const float*)d_in[12];
    const float* ln_g    = (const float*)d_in[13];
    const float* ln_b    = (const float*)d_in[14];
    const float* W0      = (const float*)d_in[15];
    const float* b0      = (const float*)d_in[16];
    const float* W1      = (const float*)d_in[17];
    const float* b1      = (const float*)d_in[18];
    const float* W_out   = (const float*)d_in[19];
    const float* b_out   = (const float*)d_in[20];

    float* ws = (float*)d_ws;
    float* q_cw    = ws + OFF_QCW;
    float* q_e     = ws + OFF_QE;
    float* q_er    = ws + OFF_QER;
    float* q_ad    = ws + OFF_QAD;
    float* l_cw    = ws + OFF_LCW;
    float* l_er    = ws + OFF_LER;
    float* l_ad    = ws + OFF_LAD;
    float* le_last = ws + OFF_LELAST;
    float* Pq      = ws + OFF_PQ;
    float* Pl      = ws + OFF_PL;

    float* out = (float*)d_out;

    k0_kernel<<<1700, 256, 0, stream>>>(q_data, qa_data, l_data,
                                        Kmat, q_embed, qa_embed,
                                        W_e, W_a, b_e, b_a,
                                        l_cw, l_er, l_ad, le_last,
                                        q_cw, q_e, q_er, q_ad);
    phaseA_kernel<<<BB*NW, 64, 0, stream>>>(M0, q_cw, q_er, q_ad,
                                            l_cw, l_er, l_ad, Pq, Pl);
    phaseB_kernel<<<NROWS_Q/8, 256, 0, stream>>>(Pq, Pl, q_e, le_last,
                                                 ln_g, ln_b, W0, b0, W1, b1,
                                                 W_out, b_out, out);
}

// Round 3
// 259.466 us; speedup vs baseline: 1.1544x; 1.1544x over previous
//
#include <hip/hip_runtime.h>
#include <math.h>

// Problem constants
#define BB 32
#define SS 50
#define LL 16
#define CC 50
#define DD 64
#define NCH 13           // c-chunks of 4 rows (C=50 padded to 52)
#define H4 256
#define NROWS_Q (BB*SS)            // 1600
#define NROWS_L (BB*SS*LL)         // 25600
#define NROWS_T (NROWS_L + NROWS_Q)

#define EA_ST 2304       // floats per (b,s) ea record: 17 rows * 128, padded to 9*256
#define W_ST  68         // floats per (b,om,s) w record: 17 * 4

// ---------------- workspace layout (floats) ----------------
#define OFF_EA     ((size_t)0)
#define OFF_W      (OFF_EA + (size_t)NROWS_Q*EA_ST)           // 3,686,400
#define OFF_PQ     (OFF_W  + (size_t)BB*NCH*SS*W_ST)          // +1,414,400
#define OFF_PL     (OFF_PQ + (size_t)NROWS_Q*DD)
#define OFF_QE     (OFF_PL + (size_t)NROWS_Q*DD)
#define OFF_LELAST (OFF_QE + (size_t)NROWS_Q*DD)
// total = 5,510,400 floats = 22.0 MB

// =====================================================================
// K0: all row-parallel precompute. One wave per row.
//   l-rows [0, NROWS_L): x = q_embed[l_data]
//   q-rows [NROWS_L, NROWS_T): xq = q_embed[q_data], xa = qa_embed[qa_data]
// Outputs packed for phaseA streaming:
//   ea[b][s][17][64] float2  (il rows 0..15 = l-side (e,a); row 16 = q-side)
//   wrec[b][om][s][17][4]    (il rows 0..15 = l-chunk w; row 16 = q-chunk w)
// Also zero-fills Pq/Pl (atomic accumulators for phaseA).
// =====================================================================
__global__ __launch_bounds__(256) void k0_kernel(
    const int* __restrict__ qd, const int* __restrict__ qadx,
    const int* __restrict__ ld,
    const float* __restrict__ Kmat, const float* __restrict__ qemb,
    const float* __restrict__ qaemb,
    const float* __restrict__ We, const float* __restrict__ Wa,
    const float* __restrict__ be, const float* __restrict__ ba,
    float* __restrict__ eaW, float* __restrict__ wrecW,
    float* __restrict__ Pzero,          // Pq base; Pq+Pl contiguous (2*1600*64)
    float* __restrict__ q_e_o, float* __restrict__ le_last)
{
    // zero the atomic accumulators (phaseA runs after this kernel completes)
    {
        int gtid = blockIdx.x*256 + threadIdx.x;
        for (int i = gtid; i < 2*NROWS_Q*DD; i += gridDim.x*256) Pzero[i] = 0.f;
    }

    __shared__ float2 sWEA[DD*DD];   // (W_e[k][d], W_a[k][d])
    __shared__ float  sK[DD*65];     // K[c][k] transposed-ish, pad 65, c>=50 zero
    int tid = threadIdx.x;
    for (int i = tid; i < DD*DD; i += 256) sWEA[i] = make_float2(We[i], Wa[i]);
    for (int i = tid; i < DD*65; i += 256) {
        int c = i / 65, k = i - c*65;
        sK[i] = (c < CC && k < DD) ? Kmat[c*DD + k] : 0.f;
    }
    __syncthreads();

    int lane = tid & 63, wv = tid >> 6;
    int wave_id = blockIdx.x*4 + wv;
    int nwaves  = gridDim.x*4;
    const float* skr = sK + lane*65;
    float bev = be[lane], bav = ba[lane];

    for (int row = wave_id; row < NROWS_T; row += nwaves) {
        if (row < NROWS_L) {
            // ---------------- l-side ----------------
            float x = qemb[(size_t)ld[row]*DD + lane];
            float er = 0.f, ad = 0.f, sc = 0.f;
            #pragma unroll
            for (int k = 0; k < DD; ++k) {
                float xk = __shfl(x, k);
                float2 w2 = sWEA[k*DD + lane];
                er = fmaf(xk, w2.x, er);
                ad = fmaf(xk, w2.y, ad);
                sc = fmaf(xk, skr[k], sc);
            }
            float s = (lane < CC) ? sc : -1e30f;
            float mx = s;
            #pragma unroll
            for (int o = 32; o >= 1; o >>= 1) mx = fmaxf(mx, __shfl_xor(mx, o));
            float p = (lane < CC) ? expf(s - mx) : 0.f;
            float sum = p;
            #pragma unroll
            for (int o = 32; o >= 1; o >>= 1) sum += __shfl_xor(sum, o);
            float wsm = p / sum;

            float erv = 1.f / (1.f + expf(-(er + bev)));
            float adv = tanhf(ad + bav);

            int bs = row >> 4, il = row & 15;
            *(float2*)(eaW + (size_t)bs*EA_ST + il*128 + lane*2) = make_float2(erv, adv);
            if (lane < 52) {
                int b = bs / SS, s2 = bs - b*SS;
                int omx = lane >> 2, j = lane & 3;
                wrecW[(((size_t)(b*NCH + omx)*SS + s2)*17 + il)*4 + j] =
                    (lane < CC) ? wsm : 0.f;
            }
            if (il == LL-1) le_last[(size_t)bs*DD + lane] = x;
        } else {
            // ---------------- q-side ----------------
            int qrow = row - NROWS_L;
            float xq = qemb [(size_t)qd  [qrow]*DD + lane];
            float xa = qaemb[(size_t)qadx[qrow]*DD + lane];
            float er = 0.f, ad = 0.f, sc = 0.f;
            #pragma unroll
            for (int k = 0; k < DD; ++k) {
                float xqk = __shfl(xq, k);
                float xak = __shfl(xa, k);
                float2 w2 = sWEA[k*DD + lane];
                er = fmaf(xak, w2.x, er);
                ad = fmaf(xak, w2.y, ad);
                sc = fmaf(xqk, skr[k], sc);
            }
            float s = (lane < CC) ? sc : -1e30f;
            float mx = s;
            #pragma unroll
            for (int o = 32; o >= 1; o >>= 1) mx = fmaxf(mx, __shfl_xor(mx, o));
            float p = (lane < CC) ? expf(s - mx) : 0.f;
            float sum = p;
            #pragma unroll
            for (int o = 32; o >= 1; o >>= 1) sum += __shfl_xor(sum, o);
            float wsm = p / sum;

            float erv = 1.f / (1.f + expf(-(er + bev)));
            float adv = tanhf(ad + bav);

            int b = qrow / SS, s2 = qrow - b*SS;
            *(float2*)(eaW + (size_t)qrow*EA_ST + 2048 + lane*2) = make_float2(erv, adv);
            if (lane < 52) {
                int omx = lane >> 2, j = lane & 3;
                wrecW[(((size_t)(b*NCH + omx)*SS + s2)*17 + 16)*4 + j] =
                    (lane < CC) ? wsm : 0.f;
            }
            q_e_o[(size_t)qrow*DD + lane] = xq;
        }
    }
}

// =====================================================================
// Phase A: sequential scan, one 64-thread block (1 wave) per (b, c-chunk).
// blockIdx = om*32 + b  -> all 13 blocks of a batch element share b%8,
// i.e. land on the same XCD under round-robin dispatch => the shared ea
// stream dedups in that XCD's L2 (perf heuristic only).
// Software pipeline: load step s+1 into regs while computing step s from
// an LDS double buffer. Single wave => no barriers; same-wave LDS ordering.
// Partial q_read/l_read reductions accumulate via atomicAdd into Pq/Pl.
// =====================================================================
__global__ __launch_bounds__(64) void phaseA_kernel(
    const float* __restrict__ M0,
    const float* __restrict__ ea, const float* __restrict__ wrec,
    float* __restrict__ Pq, float* __restrict__ Pl)
{
    int om   = blockIdx.x >> 5;     // 0..12
    int b    = blockIdx.x & 31;     // 0..31
    int lane = threadIdx.x;
    int c0   = om * 4;

    __shared__ __align__(16) float lbuf[2][EA_ST + W_ST];   // 2 x 2372 floats

    float M[4];
    #pragma unroll
    for (int i = 0; i < 4; ++i) {
        int c = c0 + i;
        M[i] = (c < CC) ? M0[c*DD + lane] : 0.f;
    }

    const float* eb = ea   + (size_t)b*SS*EA_ST;
    const float* wb = wrec + (size_t)(b*NCH + om)*SS*W_ST;
    float* pq = Pq + (size_t)b*SS*DD + lane;
    float* pl = Pl + (size_t)b*SS*DD + lane;

    // ---- prologue: stage step 0 into lbuf[0] ----
    {
        float4 r[9]; float4 rw = make_float4(0.f,0.f,0.f,0.f);
        #pragma unroll
        for (int i = 0; i < 9; ++i) r[i] = *(const float4*)(eb + i*256 + lane*4);
        if (lane < 17) rw = *(const float4*)(wb + lane*4);
        float* lb0 = &lbuf[0][0];
        #pragma unroll
        for (int i = 0; i < 9; ++i) *(float4*)(lb0 + i*256 + lane*4) = r[i];
        if (lane < 17) *(float4*)(lb0 + EA_ST + lane*4) = rw;
    }

    for (int s = 0; s < SS; ++s) {
        float* lb = &lbuf[s & 1][0];

        // ---- prefetch step s+1 into registers (overlaps compute below) ----
        float4 r[9]; float4 rw = make_float4(0.f,0.f,0.f,0.f);
        bool pf = (s < SS-1);
        if (pf) {
            const float* eg = eb + (size_t)(s+1)*EA_ST;
            const float* wg = wb + (size_t)(s+1)*W_ST;
            #pragma unroll
            for (int i = 0; i < 9; ++i) r[i] = *(const float4*)(eg + i*256 + lane*4);
            if (lane < 17) rw = *(const float4*)(wg + lane*4);
        }

        // ---- compute step s from LDS ----
        float4 qw = *(const float4*)(lb + EA_ST + 64);   // q-chunk w (il slot 16)
        float qr;
        qr = qw.x * M[0];
        qr = fmaf(qw.y, M[1], qr);
        qr = fmaf(qw.z, M[2], qr);
        qr = fmaf(qw.w, M[3], qr);

        float a0 = 0.f, a1 = 0.f, a2 = 0.f, a3 = 0.f;
        #pragma unroll
        for (int il = 0; il < 16; ++il) {
            float2 ea2 = *(const float2*)(lb + il*128 + lane*2);
            float4 w   = *(const float4*)(lb + EA_ST + il*4);
            // read (old M) partials
            a0 = fmaf(w.x, M[0], a0);
            a1 = fmaf(w.y, M[1], a1);
            a2 = fmaf(w.z, M[2], a2);
            a3 = fmaf(w.w, M[3], a3);
            // write: M = M + w*(a - e*M)
            float e = ea2.x, a = ea2.y;
            M[0] = fmaf(w.x, fmaf(-e, M[0], a), M[0]);
            M[1] = fmaf(w.y, fmaf(-e, M[1], a), M[1]);
            M[2] = fmaf(w.z, fmaf(-e, M[2], a), M[2]);
            M[3] = fmaf(w.w, fmaf(-e, M[3], a), M[3]);
        }
        float2 qea = *(const float2*)(lb + 2048 + lane*2);  // q-side (e,a), il slot 16

        atomicAdd(pq + (size_t)s*DD, qr);
        atomicAdd(pl + (size_t)s*DD, (a0 + a1) + (a2 + a3));

        // final q-write for this step
        {
            float e = qea.x, a = qea.y;
            M[0] = fmaf(qw.x, fmaf(-e, M[0], a), M[0]);
            M[1] = fmaf(qw.y, fmaf(-e, M[1], a), M[1]);
            M[2] = fmaf(qw.z, fmaf(-e, M[2], a), M[2]);
            M[3] = fmaf(qw.w, fmaf(-e, M[3], a), M[3]);
        }

        // ---- drain prefetch into the other LDS buffer ----
        if (pf) {
            float* nb = &lbuf[(s & 1) ^ 1][0];
            #pragma unroll
            for (int i = 0; i < 9; ++i) *(float4*)(nb + i*256 + lane*4) = r[i];
            if (lane < 17) *(float4*)(nb + EA_ST + lane*4) = rw;
        }
    }
}

// =====================================================================
// Phase B: mastery -> LN -> MLP -> sigmoid -> out.
// 8 rows per 256-thread block. 200 blocks.
// =====================================================================
__global__ __launch_bounds__(256) void phaseB_kernel(
    const float* __restrict__ Pq, const float* __restrict__ Pl,
    const float* __restrict__ q_e_i, const float* __restrict__ le_last,
    const float* __restrict__ ln_g, const float* __restrict__ ln_b,
    const float* __restrict__ W0, const float* __restrict__ b0,
    const float* __restrict__ W1, const float* __restrict__ b1,
    const float* __restrict__ Wout, const float* __restrict__ bout,
    float* __restrict__ out)
{
    __shared__ float m[8][H4];
    __shared__ float h[8][H4];
    __shared__ float red[8][4];

    int j = threadIdx.x;
    int g0 = blockIdx.x * 8;
    int lane = j & 63, wv = j >> 6;

    // mastery = [q_read | q_e | l_read | le_last]
    int seg = j >> 6, dd = j & 63;
    #pragma unroll
    for (int r = 0; r < 8; ++r) {
        int g = g0 + r;
        float v;
        if      (seg == 0) v = Pq[(size_t)g*DD + dd];
        else if (seg == 1) v = q_e_i[(size_t)g*DD + dd];
        else if (seg == 2) v = Pl[(size_t)g*DD + dd];
        else               v = le_last[(size_t)g*DD + dd];
        m[r][j] = v;
    }
    __syncthreads();

    // LayerNorm: wave wv normalizes rows wv and wv+4 (float4 per lane)
    #pragma unroll
    for (int rr = 0; rr < 2; ++rr) {
        int r = wv + rr*4;
        float4 v4 = *(((const float4*)&m[r][0]) + lane);
        float s1 = v4.x + v4.y + v4.z + v4.w;
        float s2 = v4.x*v4.x + v4.y*v4.y + v4.z*v4.z + v4.w*v4.w;
        #pragma unroll
        for (int o = 32; o >= 1; o >>= 1) {
            s1 += __shfl_xor(s1, o);
            s2 += __shfl_xor(s2, o);
        }
        float mu  = s1 * (1.f/256.f);
        float var = s2 * (1.f/256.f) - mu*mu;
        float is  = rsqrtf(var + 1e-5f);
        float4 g4 = *(((const float4*)ln_g) + lane);
        float4 b4 = *(((const float4*)ln_b) + lane);
        float4 o4;
        o4.x = (v4.x - mu)*is*g4.x + b4.x;
        o4.y = (v4.y - mu)*is*g4.y + b4.y;
        o4.z = (v4.z - mu)*is*g4.z + b4.z;
        o4.w = (v4.w - mu)*is*g4.w + b4.w;
        *(((float4*)&m[r][0]) + lane) = o4;
    }
    __syncthreads();

    // GEMM1: h = relu(m @ W0 + b0); thread j owns output column j, 8 rows
    float acc[8];
    {
        float bj = b0[j];
        #pragma unroll
        for (int r = 0; r < 8; ++r) acc[r] = bj;
    }
    #pragma unroll 4
    for (int k = 0; k < H4; ++k) {
        float wv0 = W0[(size_t)k*H4 + j];
        #pragma unroll
        for (int r = 0; r < 8; ++r) acc[r] = fmaf(m[r][k], wv0, acc[r]);
    }
    #pragma unroll
    for (int r = 0; r < 8; ++r) h[r][j] = fmaxf(acc[r], 0.f);
    __syncthreads();

    // GEMM2: h1 = h @ W1 + b1
    float a2[8];
    {
        float bj = b1[j];
        #pragma unroll
        for (int r = 0; r < 8; ++r) a2[r] = bj;
    }
    #pragma unroll 4
    for (int k = 0; k < H4; ++k) {
        float wv1 = W1[(size_t)k*H4 + j];
        #pragma unroll
        for (int r = 0; r < 8; ++r) a2[r] = fmaf(h[r][k], wv1, a2[r]);
    }

    // pred = sigmoid(h1 . Wout + bout)
    float wo = Wout[j];
    #pragma unroll
    for (int r = 0; r < 8; ++r) {
        float v = a2[r] * wo;
        #pragma unroll
        for (int o = 32; o >= 1; o >>= 1) v += __shfl_xor(v, o);
        if (lane == 0) red[r][wv] = v;
    }
    __syncthreads();
    if (j < 8) {
        float t = red[j][0] + red[j][1] + red[j][2] + red[j][3] + bout[0];
        out[g0 + j] = 1.f / (1.f + expf(-t));
    }
}

// =====================================================================
extern "C" void kernel_launch(void* const* d_in, const int* in_sizes, int n_in,
                              void* d_out, int out_size, void* d_ws, size_t ws_size,
                              hipStream_t stream)
{
    const int*   q_data  = (const int*)  d_in[0];
    const int*   qa_data = (const int*)  d_in[1];
    const int*   l_data  = (const int*)  d_in[2];
    // d_in[3] users: unused by reference forward
    const float* Kmat    = (const float*)d_in[4];
    const float* q_embed = (const float*)d_in[5];
    const float* qa_embed= (const float*)d_in[6];
    // d_in[7] u_embed: unused by reference forward
    const float* M0      = (const float*)d_in[8];
    const float* W_e     = (const float*)d_in[9];
    const float* b_e     = (const float*)d_in[10];
    const float* W_a     = (const float*)d_in[11];
    const float* b_a     = (const float*)d_in[12];
    const float* ln_g    = (const float*)d_in[13];
    const float* ln_b    = (const float*)d_in[14];
    const float* W0      = (const float*)d_in[15];
    const float* b0      = (const float*)d_in[16];
    const float* W1      = (const float*)d_in[17];
    const float* b1      = (const float*)d_in[18];
    const float* W_out   = (const float*)d_in[19];
    const float* b_out   = (const float*)d_in[20];

    float* ws = (float*)d_ws;
    float* eaW     = ws + OFF_EA;
    float* wrecW   = ws + OFF_W;
    float* Pq      = ws + OFF_PQ;
    float* Pl      = ws + OFF_PL;
    float* q_e     = ws + OFF_QE;
    float* le_last = ws + OFF_LELAST;

    float* out = (float*)d_out;

    k0_kernel<<<1700, 256, 0, stream>>>(q_data, qa_data, l_data,
                                        Kmat, q_embed, qa_embed,
                                        W_e, W_a, b_e, b_a,
                                        eaW, wrecW, Pq,      // Pq..Pl zeroed
                                        q_e, le_last);
    phaseA_kernel<<<BB*NCH, 64, 0, stream>>>(M0, eaW, wrecW, Pq, Pl);
    phaseB_kernel<<<NROWS_Q/8, 256, 0, stream>>>(Pq, Pl, q_e, le_last,
                                                 ln_g, ln_b, W0, b0, W1, b1,
                                                 W_out, b_out, out);
}

// Round 5
// 222.248 us; speedup vs baseline: 1.3477x; 1.1675x over previous
//
#include <hip/hip_runtime.h>
#include <math.h>

// Problem constants
#define BB 32
#define SS 50
#define LL 16
#define CC 50
#define DD 64
#define NCH 13           // c-chunks of 4 rows (C=50 padded to 52)
#define H4 256
#define NROWS_Q (BB*SS)            // 1600
#define NROWS_L (BB*SS*LL)         // 25600

#define EA_ST 2304       // floats per (b,s) ea record: 17 slots * 128, padded
#define W_ST  68         // floats per (b,om,s) w record: 17 * 4

// GEMM geometry for k0
#define RB 64                       // rows per block
#define NBLK_L (NROWS_L/RB)         // 400
#define NBLK_Q (NROWS_Q/RB)         // 25
#define NGB (NBLK_L + 2*NBLK_Q)     // 450

// Layout invariants shared by k0 (producer) and phaseA (consumer)
static_assert(EA_ST == 17*128 + 128, "ea record: 17 slots x 64 lanes x float2, +pad");
static_assert(W_ST == 17*4, "w record: 17 slots x 4 chunk-cols");
static_assert(SS % 2 == 0, "phaseA double-step pipeline needs even SS");
static_assert(NROWS_L % RB == 0 && NROWS_Q % RB == 0, "GEMM row blocking");

// ---------------- workspace layout (floats) ----------------
#define OFF_EA     ((size_t)0)
#define OFF_W      (OFF_EA + (size_t)NROWS_Q*EA_ST)
#define OFF_PQ     (OFF_W  + (size_t)BB*NCH*SS*W_ST)
#define OFF_PL     (OFF_PQ + (size_t)NROWS_Q*DD)
#define OFF_QE     (OFF_PL + (size_t)NROWS_Q*DD)
#define OFF_LELAST (OFF_QE + (size_t)NROWS_Q*DD)
// total = 5,510,400 floats = 22.0 MB

// =====================================================================
// K0: all row-parallel precompute as ONE register-tile GEMM + row stage.
// Row space (28800 rows = 450 blocks x 64):
//   blocks [0,400):   l-rows, x = q_embed[l_data]   (all outputs used)
//   blocks [400,425): q-sc rows, x = q_embed[q_data]  (softmax cols used)
//   blocks [425,450): q-ea rows, x = qa_embed[qa_data] (er/ad cols used)
// Wcat[64][192] = [W_e | W_a | K^T | 0pad], staged k4-interleaved in LDS:
//   sW[k4*768 + c*4 + j] = Wcat[4*k4+j][c]   (bank-balanced b128 reads)
// Each thread: 8 rows x 6 cols micro-tile => 192 fma per 14 LDS b128.
// Stage 2: per-row wave softmax/sigmoid/tanh + packing.
// =====================================================================
__global__ __launch_bounds__(256) void k0_kernel(
    const int* __restrict__ qd, const int* __restrict__ qadx,
    const int* __restrict__ ld,
    const float* __restrict__ Kmat, const float* __restrict__ qemb,
    const float* __restrict__ qaemb,
    const float* __restrict__ We, const float* __restrict__ Wa,
    const float* __restrict__ be, const float* __restrict__ ba,
    float* __restrict__ eaW, float* __restrict__ wrecW,
    float* __restrict__ Pzero,          // Pq base; Pq+Pl contiguous
    float* __restrict__ q_e_o, float* __restrict__ le_last)
{
    __shared__ float smem[16384];       // 64 KB: [X 16K | W 48K -> Out 48K]
    float* sX   = smem;                 // [64][64]
    float* sW   = smem + 4096;          // [16][192][4] k4-interleaved
    float* sOut = smem + 4096;          // aliases sW after the k-loop: [64][192]

    int tid = threadIdx.x;
    int bid = blockIdx.x;

    // zero the phaseA atomic accumulators (Pq,Pl contiguous)
    for (int i = bid*256 + tid; i < 2*NROWS_Q*DD; i += NGB*256) Pzero[i] = 0.f;

    int bt, base;
    if (bid < NBLK_L)              { bt = 0; base = bid*RB; }
    else if (bid < NBLK_L+NBLK_Q)  { bt = 1; base = (bid-NBLK_L)*RB; }
    else                           { bt = 2; base = (bid-NBLK_L-NBLK_Q)*RB; }

    // ---- stage X tile (embedding gather) ----
    {
        const int*   idsrc = (bt==0) ? ld : (bt==1) ? qd : qadx;
        const float* tab   = (bt==2) ? qaemb : qemb;
        for (int idx = tid; idx < RB*16; idx += 256) {
            int r = idx >> 4, q = idx & 15;
            int id = idsrc[base + r];
            *(float4*)(sX + r*64 + q*4) =
                *(const float4*)(tab + (size_t)id*DD + q*4);
        }
    }
    // ---- stage Wcat (k4-interleaved) ----
    for (int i = tid; i < 12288; i += 256) {
        int k4 = i / 768, rem = i - k4*768;
        int c = rem >> 2, j = rem & 3;
        int k = k4*4 + j;
        float v;
        if      (c < 64)  v = We[k*64 + c];
        else if (c < 128) v = Wa[k*64 + (c-64)];
        else if (c < 178) v = Kmat[(c-128)*64 + k];
        else              v = 0.f;
        sW[i] = v;
    }
    __syncthreads();

    // ---- GEMM: out[r][c] = sum_k X[r][k]*Wcat[k][c] ----
    int rg = tid >> 5, cg = tid & 31;
    int r0 = rg*8, c0 = cg*6;
    float acc[8][6];
    #pragma unroll
    for (int i = 0; i < 8; ++i)
        #pragma unroll
        for (int c = 0; c < 6; ++c) acc[i][c] = 0.f;

    #pragma unroll 2
    for (int k4 = 0; k4 < 16; ++k4) {
        float4 xv[8], wv[6];
        #pragma unroll
        for (int i = 0; i < 8; ++i)
            xv[i] = *(const float4*)(sX + (r0+i)*64 + k4*4);
        #pragma unroll
        for (int c = 0; c < 6; ++c)
            wv[c] = *(const float4*)(sW + k4*768 + (c0+c)*4);
        #pragma unroll
        for (int i = 0; i < 8; ++i)
            #pragma unroll
            for (int c = 0; c < 6; ++c) {
                acc[i][c] = fmaf(xv[i].x, wv[c].x, acc[i][c]);
                acc[i][c] = fmaf(xv[i].y, wv[c].y, acc[i][c]);
                acc[i][c] = fmaf(xv[i].z, wv[c].z, acc[i][c]);
                acc[i][c] = fmaf(xv[i].w, wv[c].w, acc[i][c]);
            }
    }
    __syncthreads();            // all waves done reading sW
    #pragma unroll
    for (int i = 0; i < 8; ++i)
        #pragma unroll
        for (int c = 0; c < 6; ++c)
            sOut[(r0+i)*192 + c0 + c] = acc[i][c];
    __syncthreads();

    // ---- stage 2: per-row nonlinearity + packing; wave per row ----
    int lane = tid & 63, wvi = tid >> 6;
    float bev = be[lane], bav = ba[lane];

    auto rowsoftmax = [&](const float* orow) -> float {
        float sc = orow[128 + lane];
        float s = (lane < CC) ? sc : -1e30f;
        float mx = s;
        #pragma unroll
        for (int o = 32; o >= 1; o >>= 1) mx = fmaxf(mx, __shfl_xor(mx, o));
        float p = (lane < CC) ? expf(s - mx) : 0.f;
        float sum = p;
        #pragma unroll
        for (int o = 32; o >= 1; o >>= 1) sum += __shfl_xor(sum, o);
        return p / sum;
    };

    for (int i = 0; i < 16; ++i) {
        int rr = wvi*16 + i;
        int grow = base + rr;
        const float* orow = sOut + rr*192;

        if (bt == 0) {
            float erv = 1.f / (1.f + expf(-(orow[lane] + bev)));
            float adv = tanhf(orow[64 + lane] + bav);
            float wsm = rowsoftmax(orow);
            int bs = grow >> 4, il = grow & 15;
            *(float2*)(eaW + (size_t)bs*EA_ST + il*128 + lane*2) =
                make_float2(erv, adv);
            int b = bs / SS, s2 = bs - b*SS;
            if (lane < 52) {
                int omx = lane >> 2, j = lane & 3;
                wrecW[(((size_t)(b*NCH + omx)*SS + s2)*17 + il)*4 + j] =
                    (lane < CC) ? wsm : 0.f;
            }
            if (il == LL-1) le_last[(size_t)bs*DD + lane] = sX[rr*64 + lane];
        } else if (bt == 1) {
            float wsm = rowsoftmax(orow);
            int qrow = grow;
            int b = qrow / SS, s2 = qrow - b*SS;
            if (lane < 52) {
                int omx = lane >> 2, j = lane & 3;
                wrecW[(((size_t)(b*NCH + omx)*SS + s2)*17 + 16)*4 + j] =
                    (lane < CC) ? wsm : 0.f;
            }
            q_e_o[(size_t)qrow*DD + lane] = sX[rr*64 + lane];
        } else {
            float erv = 1.f / (1.f + expf(-(orow[lane] + bev)));
            float adv = tanhf(orow[64 + lane] + bav);
            int qrow = grow;
            *(float2*)(eaW + (size_t)qrow*EA_ST + 2048 + lane*2) =
                make_float2(erv, adv);
        }
    }
}

// =====================================================================
// Phase A: sequential scan, one 64-thread block (1 wave) per (b, c-chunk).
// blockIdx = om*32 + b -> the 13 blocks of a batch element share b%8
// (same XCD under round-robin) so the shared ea stream dedups in L2.
// ea: register double-buffer (17 x float2), prefetched 1 step ahead with
// coalesced dwordx2 loads. w-record: tiny LDS double-buffer, broadcast
// reads; its global load is issued early, LDS write after compute.
// Single wave => no barriers. Partials accumulate via atomicAdd.
// =====================================================================
__global__ __launch_bounds__(64) void phaseA_kernel(
    const float* __restrict__ M0,
    const float* __restrict__ ea, const float* __restrict__ wrec,
    float* __restrict__ Pq, float* __restrict__ Pl)
{
    int om   = blockIdx.x >> 5;     // 0..12
    int b    = blockIdx.x & 31;     // 0..31
    int lane = threadIdx.x;
    int c0   = om * 4;

    __shared__ __align__(16) float wbuf[2][W_ST];

    float M[4];
    #pragma unroll
    for (int i = 0; i < 4; ++i) {
        int c = c0 + i;
        M[i] = (c < CC) ? M0[c*DD + lane] : 0.f;
    }

    const float* eb = ea   + (size_t)b*SS*EA_ST + lane*2;
    const float* wb = wrec + (size_t)(b*NCH + om)*SS*W_ST;
    float* pq = Pq + (size_t)b*SS*DD + lane;
    float* pl = Pl + (size_t)b*SS*DD + lane;

    float2 ea0[17], ea1[17];

    // prologue: load step 0 (ea -> regs, w -> wbuf[0])
    #pragma unroll
    for (int il = 0; il < 17; ++il)
        ea0[il] = *(const float2*)(eb + il*128);
    if (lane < 17)
        *(float4*)&wbuf[0][lane*4] = *(const float4*)(wb + lane*4);

    auto step = [&](int s, float2 (&cur)[17], float2 (&nxt)[17], int wbsel) {
        bool pf = (s < SS-1);
        float4 rw;
        if (pf) {
            const float* eg = eb + (size_t)(s+1)*EA_ST;
            #pragma unroll
            for (int il = 0; il < 17; ++il)
                nxt[il] = *(const float2*)(eg + il*128);
            if (lane < 17)
                rw = *(const float4*)(wb + (size_t)(s+1)*W_ST + lane*4);
        }

        // ---- compute step s ----
        float4 qw = *(const float4*)&wbuf[wbsel][64];   // q-chunk w (slot 16)
        float qr;
        qr = qw.x * M[0];
        qr = fmaf(qw.y, M[1], qr);
        qr = fmaf(qw.z, M[2], qr);
        qr = fmaf(qw.w, M[3], qr);

        float a0 = 0.f, a1 = 0.f, a2 = 0.f, a3 = 0.f;
        #pragma unroll
        for (int il = 0; il < 16; ++il) {
            float4 w = *(const float4*)&wbuf[wbsel][il*4];
            float e = cur[il].x, a = cur[il].y;
            a0 = fmaf(w.x, M[0], a0);
            a1 = fmaf(w.y, M[1], a1);
            a2 = fmaf(w.z, M[2], a2);
            a3 = fmaf(w.w, M[3], a3);
            M[0] = fmaf(w.x, fmaf(-e, M[0], a), M[0]);
            M[1] = fmaf(w.y, fmaf(-e, M[1], a), M[1]);
            M[2] = fmaf(w.z, fmaf(-e, M[2], a), M[2]);
            M[3] = fmaf(w.w, fmaf(-e, M[3], a), M[3]);
        }

        atomicAdd(pq + (size_t)s*DD, qr);
        atomicAdd(pl + (size_t)s*DD, (a0 + a1) + (a2 + a3));

        { // final q-write
            float e = cur[16].x, a = cur[16].y;
            M[0] = fmaf(qw.x, fmaf(-e, M[0], a), M[0]);
            M[1] = fmaf(qw.y, fmaf(-e, M[1], a), M[1]);
            M[2] = fmaf(qw.z, fmaf(-e, M[2], a), M[2]);
            M[3] = fmaf(qw.w, fmaf(-e, M[3], a), M[3]);
        }

        // write next w-record late (vmcnt wait lands after compute)
        if (pf && lane < 17)
            *(float4*)&wbuf[wbsel ^ 1][lane*4] = rw;
    };

    for (int s = 0; s < SS; s += 2) {
        step(s,     ea0, ea1, 0);
        step(s + 1, ea1, ea0, 1);
    }
}

// =====================================================================
// Phase B: mastery -> LN -> MLP -> sigmoid -> out.
// 8 rows per 256-thread block. 200 blocks.
// =====================================================================
__global__ __launch_bounds__(256) void phaseB_kernel(
    const float* __restrict__ Pq, const float* __restrict__ Pl,
    const float* __restrict__ q_e_i, const float* __restrict__ le_last,
    const float* __restrict__ ln_g, const float* __restrict__ ln_b,
    const float* __restrict__ W0, const float* __restrict__ b0,
    const float* __restrict__ W1, const float* __restrict__ b1,
    const float* __restrict__ Wout, const float* __restrict__ bout,
    float* __restrict__ out)
{
    __shared__ float m[8][H4];
    __shared__ float h[8][H4];
    __shared__ float red[8][4];

    int j = threadIdx.x;
    int g0 = blockIdx.x * 8;
    int lane = j & 63, wv = j >> 6;

    // mastery = [q_read | q_e | l_read | le_last]
    int seg = j >> 6, dd = j & 63;
    #pragma unroll
    for (int r = 0; r < 8; ++r) {
        int g = g0 + r;
        float v;
        if      (seg == 0) v = Pq[(size_t)g*DD + dd];
        else if (seg == 1) v = q_e_i[(size_t)g*DD + dd];
        else if (seg == 2) v = Pl[(size_t)g*DD + dd];
        else               v = le_last[(size_t)g*DD + dd];
        m[r][j] = v;
    }
    __syncthreads();

    // LayerNorm: wave wv normalizes rows wv and wv+4
    #pragma unroll
    for (int rr = 0; rr < 2; ++rr) {
        int r = wv + rr*4;
        float4 v4 = *(((const float4*)&m[r][0]) + lane);
        float s1 = v4.x + v4.y + v4.z + v4.w;
        float s2 = v4.x*v4.x + v4.y*v4.y + v4.z*v4.z + v4.w*v4.w;
        #pragma unroll
        for (int o = 32; o >= 1; o >>= 1) {
            s1 += __shfl_xor(s1, o);
            s2 += __shfl_xor(s2, o);
        }
        float mu  = s1 * (1.f/256.f);
        float var = s2 * (1.f/256.f) - mu*mu;
        float is  = rsqrtf(var + 1e-5f);
        float4 g4 = *(((const float4*)ln_g) + lane);
        float4 b4 = *(((const float4*)ln_b) + lane);
        float4 o4;
        o4.x = (v4.x - mu)*is*g4.x + b4.x;
        o4.y = (v4.y - mu)*is*g4.y + b4.y;
        o4.z = (v4.z - mu)*is*g4.z + b4.z;
        o4.w = (v4.w - mu)*is*g4.w + b4.w;
        *(((float4*)&m[r][0]) + lane) = o4;
    }
    __syncthreads();

    // GEMM1: h = relu(m @ W0 + b0)
    float acc[8];
    {
        float bj = b0[j];
        #pragma unroll
        for (int r = 0; r < 8; ++r) acc[r] = bj;
    }
    #pragma unroll 4
    for (int k = 0; k < H4; ++k) {
        float wv0 = W0[(size_t)k*H4 + j];
        #pragma unroll
        for (int r = 0; r < 8; ++r) acc[r] = fmaf(m[r][k], wv0, acc[r]);
    }
    #pragma unroll
    for (int r = 0; r < 8; ++r) h[r][j] = fmaxf(acc[r], 0.f);
    __syncthreads();

    // GEMM2: h1 = h @ W1 + b1
    float a2[8];
    {
        float bj = b1[j];
        #pragma unroll
        for (int r = 0; r < 8; ++r) a2[r] = bj;
    }
    #pragma unroll 4
    for (int k = 0; k < H4; ++k) {
        float wv1 = W1[(size_t)k*H4 + j];
        #pragma unroll
        for (int r = 0; r < 8; ++r) a2[r] = fmaf(h[r][k], wv1, a2[r]);
    }

    // pred = sigmoid(h1 . Wout + bout)
    float wo = Wout[j];
    #pragma unroll
    for (int r = 0; r < 8; ++r) {
        float v = a2[r] * wo;
        #pragma unroll
        for (int o = 32; o >= 1; o >>= 1) v += __shfl_xor(v, o);
        if (lane == 0) red[r][wv] = v;
    }
    __syncthreads();
    if (j < 8) {
        float t = red[j][0] + red[j][1] + red[j][2] + red[j][3] + bout[0];
        out[g0 + j] = 1.f / (1.f + expf(-t));
    }
}

// =====================================================================
extern "C" void kernel_launch(void* const* d_in, const int* in_sizes, int n_in,
                              void* d_out, int out_size, void* d_ws, size_t ws_size,
                              hipStream_t stream)
{
    const int*   q_data  = (const int*)  d_in[0];
    const int*   qa_data = (const int*)  d_in[1];
    const int*   l_data  = (const int*)  d_in[2];
    // d_in[3] users: unused by reference forward
    const float* Kmat    = (const float*)d_in[4];
    const float* q_embed = (const float*)d_in[5];
    const float* qa_embed= (const float*)d_in[6];
    // d_in[7] u_embed: unused by reference forward
    const float* M0      = (const float*)d_in[8];
    const float* W_e     = (const float*)d_in[9];
    const float* b_e     = (const float*)d_in[10];
    const float* W_a     = (const float*)d_in[11];
    const float* b_a     = (const float*)d_in[12];
    const float* ln_g    = (const float*)d_in[13];
    const float* ln_b    = (const float*)d_in[14];
    const float* W0      = (const float*)d_in[15];
    const float* b0      = (const float*)d_in[16];
    const float* W1      = (const float*)d_in[17];
    const float* b1      = (const float*)d_in[18];
    const float* W_out   = (const float*)d_in[19];
    const float* b_out   = (const float*)d_in[20];

    float* ws = (float*)d_ws;
    float* eaW     = ws + OFF_EA;
    float* wrecW   = ws + OFF_W;
    float* Pq      = ws + OFF_PQ;
    float* Pl      = ws + OFF_PL;
    float* q_e     = ws + OFF_QE;
    float* le_last = ws + OFF_LELAST;

    float* out = (float*)d_out;

    k0_kernel<<<NGB, 256, 0, stream>>>(q_data, qa_data, l_data,
                                       Kmat, q_embed, qa_embed,
                                       W_e, W_a, b_e, b_a,
                                       eaW, wrecW, Pq,
                                       q_e, le_last);
    phaseA_kernel<<<BB*NCH, 64, 0, stream>>>(M0, eaW, wrecW, Pq, Pl);
    phaseB_kernel<<<NROWS_Q/8, 256, 0, stream>>>(Pq, Pl, q_e, le_last,
                                                 ln_g, ln_b, W0, b0, W1, b1,
                                                 W_out, b_out, out);
}